// Round 7
// baseline (337.618 us; speedup 1.0000x reference)
//
#include <hip/hip_runtime.h>
#include <math.h>

// ---------------------------------------------------------------------------
// HashGrid INR fused kernel for MI355X (gfx950) — round 7
//   bf16x3 split on 32x32x16 MFMA; wave = (pt,cg): 32 points x 64 cols
//   (halves LDS act traffic; weight redundancy absorbed by L1);
//   explicit next-step register prefetch for acts AND weights.
// ---------------------------------------------------------------------------

typedef __bf16 bf16x8 __attribute__((ext_vector_type(8)));
typedef float  f32x16 __attribute__((ext_vector_type(16)));
typedef unsigned int u32x4 __attribute__((ext_vector_type(4)));
typedef unsigned int u32x2 __attribute__((ext_vector_type(2)));

struct LevelParams {
  float res[16];
  unsigned hsize[16];
  unsigned M[8];     // magic multiplier for levels 0..7
  unsigned c16[8];   // 65536 % d
  int      sh[8];    // post-mulhi shift
};

static constexpr int MTILE = 64;          // points per block
static constexpr int LDA   = 264;         // act row stride (elems); 528B = 33x16B slots
static constexpr int ACT_ELEMS = MTILE * LDA;
// pack unit = (s, cq): 32 cols x 16 k, [hi 512 | lo 512] bf16 = 2KB
// L0: 3 s x 8 cq = 24 units; L1..L3: 16 x 8 = 128 each
static constexpr int UB_L0 = 0, UB_L1 = 24, UB_L2 = 152, UB_L3 = 280;
static constexpr int UNITS_TOTAL = 408;

__device__ __forceinline__ unsigned short f32_to_bf16_rne(float f) {
  unsigned u = __float_as_uint(f);
  unsigned r = (u + 0x7fffu + ((u >> 16) & 1u)) >> 16;
  return (unsigned short)r;
}
__device__ __forceinline__ float bf16_bits_to_f32(unsigned u16bits) {
  return __uint_as_float(u16bits << 16);
}
__device__ __forceinline__ unsigned pack_hi(unsigned u0, unsigned u1) {
  return (u0 >> 16) | (u1 & 0xffff0000u);   // trunc bf16 of (v0,v1) packed
}

// --------------------------- weight packing --------------------------------
// mapping: out-col = cq*32 + (l&31), k = s*16 + 8*(l>>5) + e
__global__ void prep_pack(const float* __restrict__ W0, const float* __restrict__ W1,
                          const float* __restrict__ W2, const float* __restrict__ W3,
                          unsigned short* __restrict__ pack) {
  int b = blockIdx.x;
  int l = threadIdx.x;
  const float* W; int K, s, cq;
  if (b < UB_L1) { W = W0; K = 33; s = b >> 3; cq = b & 7; }
  else {
    int b2 = b - UB_L1; int ly = b2 >> 7; int r = b2 & 127;
    W = (ly == 0) ? W1 : (ly == 1) ? W2 : W3; K = 256; s = r >> 3; cq = r & 7;
  }
  int col = (cq << 5) + (l & 31);
  int kb  = (s << 4) + ((l >> 5) << 3);
  unsigned short* dst = pack + (size_t)b * 1024 + l * 8;
#pragma unroll
  for (int e = 0; e < 8; ++e) {
    int k = kb + e;
    float v = (k < K) ? W[k * 256 + col] : 0.0f;
    unsigned u = __float_as_uint(v);
    unsigned short h = (unsigned short)(u >> 16);           // truncation hi
    float hf = bf16_bits_to_f32(u >> 16);
    unsigned short lo = f32_to_bf16_rne(v - hf);
    dst[e]       = h;
    dst[512 + e] = lo;
  }
}

// ------------------------------ layer body ---------------------------------
// wave (pt,cg): points [pt*32, pt*32+32), cols [cg*64, cg*64+64) (2 chains).
// A = weights (lane&31 -> out channel), B = acts (lane&31 -> point).
// D (32x32): col = lane&31 = point; row = (r&3)+8*(r>>2)+4*(lane>>5) = channel.
template<int S>
__device__ __forceinline__ void run_layer(unsigned short* __restrict__ ahi,
                                          unsigned short* __restrict__ alo,
                                          const unsigned short* __restrict__ pack,
                                          int ubase,
                                          const float* __restrict__ bias,
                                          int pt, int cg, int l) {
  f32x16 acc0 = (f32x16)0.0f, acc1 = (f32x16)0.0f;
  const int i31 = l & 31, p = l >> 5;
  const int arow = (pt << 5) + i31;

  const unsigned short* ah_base = ahi + arow * LDA + (p << 3);
  const unsigned short* al_base = alo + arow * LDA + (p << 3);
  const unsigned short* wb = pack + (size_t)(ubase + (cg << 1)) * 1024 + l * 8;

  // current-step operands (prefetched pipeline; step stride = 8 units = 8192)
  u32x4 wh0 = *(const u32x4*)(wb);
  u32x4 wl0 = *(const u32x4*)(wb + 512);
  u32x4 wh1 = *(const u32x4*)(wb + 1024);
  u32x4 wl1 = *(const u32x4*)(wb + 1536);
  u32x4 cah = *(const u32x4*)(ah_base);
  u32x4 cal = *(const u32x4*)(al_base);

#pragma unroll
  for (int s = 0; s < S; ++s) {
    u32x4 nh0 = wh0, nl0 = wl0, nh1 = wh1, nl1 = wl1, nah = cah, nal = cal;
    if (s + 1 < S) {
      const unsigned short* wn = wb + (size_t)(s + 1) * 8192;
      nh0 = *(const u32x4*)(wn);
      nl0 = *(const u32x4*)(wn + 512);
      nh1 = *(const u32x4*)(wn + 1024);
      nl1 = *(const u32x4*)(wn + 1536);
      nah = *(const u32x4*)(ah_base + ((s + 1) << 4));
      nal = *(const u32x4*)(al_base + ((s + 1) << 4));
    }
    bf16x8 AH = __builtin_bit_cast(bf16x8, cah);
    bf16x8 AL = __builtin_bit_cast(bf16x8, cal);
    acc0 = __builtin_amdgcn_mfma_f32_32x32x16_bf16(__builtin_bit_cast(bf16x8, wh0), AH, acc0, 0, 0, 0);
    acc1 = __builtin_amdgcn_mfma_f32_32x32x16_bf16(__builtin_bit_cast(bf16x8, wh1), AH, acc1, 0, 0, 0);
    acc0 = __builtin_amdgcn_mfma_f32_32x32x16_bf16(__builtin_bit_cast(bf16x8, wl0), AH, acc0, 0, 0, 0);
    acc1 = __builtin_amdgcn_mfma_f32_32x32x16_bf16(__builtin_bit_cast(bf16x8, wl1), AH, acc1, 0, 0, 0);
    acc0 = __builtin_amdgcn_mfma_f32_32x32x16_bf16(__builtin_bit_cast(bf16x8, wh0), AL, acc0, 0, 0, 0);
    acc1 = __builtin_amdgcn_mfma_f32_32x32x16_bf16(__builtin_bit_cast(bf16x8, wh1), AL, acc1, 0, 0, 0);
    wh0 = nh0; wl0 = nl0; wh1 = nh1; wl1 = nl1; cah = nah; cal = nal;
  }
  __syncthreads();   // all reads of act done -> safe to overwrite

#pragma unroll
  for (int ct = 0; ct < 2; ++ct) {
    f32x16 A = ct ? acc1 : acc0;          // ct is unroll-constant
#pragma unroll
    for (int g = 0; g < 4; ++g) {
      int chb = (cg << 6) + (ct << 5) + (g << 3) + (p << 2);
      float4 bv = *(const float4*)(bias + chb);
      float v0 = fmaxf(A[4 * g + 0] + bv.x, 0.0f);
      float v1 = fmaxf(A[4 * g + 1] + bv.y, 0.0f);
      float v2 = fmaxf(A[4 * g + 2] + bv.z, 0.0f);
      float v3 = fmaxf(A[4 * g + 3] + bv.w, 0.0f);
      unsigned u0 = __float_as_uint(v0), u1 = __float_as_uint(v1);
      unsigned u2 = __float_as_uint(v2), u3 = __float_as_uint(v3);
      u32x2 hw = { pack_hi(u0, u1), pack_hi(u2, u3) };
      float l0 = v0 - __uint_as_float(u0 & 0xffff0000u);
      float l1 = v1 - __uint_as_float(u1 & 0xffff0000u);
      float l2 = v2 - __uint_as_float(u2 & 0xffff0000u);
      float l3 = v3 - __uint_as_float(u3 & 0xffff0000u);
      u32x2 lw = { pack_hi(__float_as_uint(l0), __float_as_uint(l1)),
                   pack_hi(__float_as_uint(l2), __float_as_uint(l3)) };
      int base = arow * LDA + chb;
      *(u32x2*)(ahi + base) = hw;
      *(u32x2*)(alo + base) = lw;
    }
  }
  __syncthreads();
}

// ------------------------------ main kernel --------------------------------
__global__ __launch_bounds__(512, 4) void inr_main(
    const float* __restrict__ x, const float* __restrict__ tables,
    const float* __restrict__ b0, const float* __restrict__ b1,
    const float* __restrict__ b2, const float* __restrict__ b3,
    const float* __restrict__ W4, const float* __restrict__ b4,
    const unsigned short* __restrict__ pack, float* __restrict__ out,
    LevelParams P) {
  extern __shared__ char smem[];
  unsigned short* ahi = (unsigned short*)smem;
  unsigned short* alo = ahi + ACT_ELEMS;

  const int tid = threadIdx.x;

  // -------- encode: 8 threads/point; thread q does level q (magic) + q+8 (AND)
  {
    int pl = tid >> 3, q = tid & 7;
    size_t pidx = (size_t)blockIdx.x * MTILE + pl;
    float x0 = x[3 * pidx + 0], x1 = x[3 * pidx + 1], x2 = x[3 * pidx + 2];
    float f_lo0, f_lo1, f_hi0, f_hi1;

    {   // level q: hashed, exact magic modulo
      float rf = P.res[q];
      unsigned d = P.hsize[q], c = P.c16[q], M = P.M[q];
      int sh = P.sh[q];
      float xs0 = x0 * rf, xs1 = x1 * rf;
      float fl0 = floorf(xs0), fl1 = floorf(xs1);
      float f0 = xs0 - fl0, f1 = xs1 - fl1;
      int i0 = (int)fl0, i1 = (int)fl1;
      unsigned ua0 = (unsigned)i0, ua1 = (unsigned)(i0 + 1);
      unsigned vb0 = (unsigned)i1 * 2654435761u;
      unsigned vb1 = (unsigned)(i1 + 1) * 2654435761u;
      const float* tl = tables + ((size_t)q << 13);
      float g0 = 1.0f - f0, g1 = 1.0f - f1;
      unsigned e0 = ua0 ^ vb0, e1 = ua0 ^ vb1, e2 = ua1 ^ vb0, e3 = ua1 ^ vb1;
      unsigned n0 = (e0 >> 16) * c + (e0 & 0xffffu);
      unsigned n1 = (e1 >> 16) * c + (e1 & 0xffffu);
      unsigned n2 = (e2 >> 16) * c + (e2 & 0xffffu);
      unsigned n3 = (e3 >> 16) * c + (e3 & 0xffffu);
      unsigned h0 = n0 - (__umulhi(n0, M) >> sh) * d;
      unsigned h1 = n1 - (__umulhi(n1, M) >> sh) * d;
      unsigned h2 = n2 - (__umulhi(n2, M) >> sh) * d;
      unsigned h3 = n3 - (__umulhi(n3, M) >> sh) * d;
      float a0 = 0.0f, a1 = 0.0f;
      { float w = g0 * g1; a0 += w * tl[2*h0]; a1 += w * tl[2*h0+1]; }
      { float w = g0 * f1; a0 += w * tl[2*h1]; a1 += w * tl[2*h1+1]; }
      { float w = f0 * g1; a0 += w * tl[2*h2]; a1 += w * tl[2*h2+1]; }
      { float w = f0 * f1; a0 += w * tl[2*h3]; a1 += w * tl[2*h3+1]; }
      f_lo0 = a0; f_lo1 = a1;
    }
    {   // level q+8: hsize == 4096 -> AND
      int lv = q + 8;
      float rf = P.res[lv];
      float xs0 = x0 * rf, xs1 = x1 * rf;
      float fl0 = floorf(xs0), fl1 = floorf(xs1);
      float f0 = xs0 - fl0, f1 = xs1 - fl1;
      int i0 = (int)fl0, i1 = (int)fl1;
      unsigned ua0 = (unsigned)i0, ua1 = (unsigned)(i0 + 1);
      unsigned vb0 = (unsigned)i1 * 2654435761u;
      unsigned vb1 = (unsigned)(i1 + 1) * 2654435761u;
      const float* tl = tables + ((size_t)lv << 13);
      float g0 = 1.0f - f0, g1 = 1.0f - f1;
      unsigned h0 = (ua0 ^ vb0) & 4095u, h1 = (ua0 ^ vb1) & 4095u;
      unsigned h2 = (ua1 ^ vb0) & 4095u, h3 = (ua1 ^ vb1) & 4095u;
      float a0 = 0.0f, a1 = 0.0f;
      { float w = g0 * g1; a0 += w * tl[2*h0]; a1 += w * tl[2*h0+1]; }
      { float w = g0 * f1; a0 += w * tl[2*h1]; a1 += w * tl[2*h1+1]; }
      { float w = f0 * g1; a0 += w * tl[2*h2]; a1 += w * tl[2*h2+1]; }
      { float w = f0 * f1; a0 += w * tl[2*h3]; a1 += w * tl[2*h3+1]; }
      f_hi0 = a0; f_hi1 = a1;
    }
    {   // store: level q -> cols {2q,2q+1}; level q+8 -> cols {16+2q,17+2q}
      int rowb = pl * LDA;
      unsigned u0 = __float_as_uint(f_lo0), u1 = __float_as_uint(f_lo1);
      unsigned u2 = __float_as_uint(f_hi0), u3 = __float_as_uint(f_hi1);
      float l0 = f_lo0 - __uint_as_float(u0 & 0xffff0000u);
      float l1 = f_lo1 - __uint_as_float(u1 & 0xffff0000u);
      float l2 = f_hi0 - __uint_as_float(u2 & 0xffff0000u);
      float l3 = f_hi1 - __uint_as_float(u3 & 0xffff0000u);
      *(unsigned*)(ahi + rowb + 2*q)      = pack_hi(u0, u1);
      *(unsigned*)(ahi + rowb + 16 + 2*q) = pack_hi(u2, u3);
      *(unsigned*)(alo + rowb + 2*q)      = pack_hi(__float_as_uint(l0), __float_as_uint(l1));
      *(unsigned*)(alo + rowb + 16 + 2*q) = pack_hi(__float_as_uint(l2), __float_as_uint(l3));
    }
    {   // tail cols 32..47: [x2, 0, 0, ...]; thread q covers {32+2q, 33+2q}
      int base = pl * LDA + 32 + 2*q;
      if (q == 0) {
        unsigned u0 = __float_as_uint(x2);
        float l0 = x2 - __uint_as_float(u0 & 0xffff0000u);
        *(unsigned*)(ahi + base) = u0 >> 16;
        *(unsigned*)(alo + base) = __float_as_uint(l0) >> 16;
      } else {
        *(unsigned*)(ahi + base) = 0u;
        *(unsigned*)(alo + base) = 0u;
      }
    }
  }
  __syncthreads();

  const int l  = tid & 63;
  const int w  = tid >> 6;
  const int pt = w & 1;       // point half
  const int cg = w >> 1;      // 64-col group

  run_layer<3>(ahi, alo, pack, UB_L0, b0, pt, cg, l);
  run_layer<16>(ahi, alo, pack, UB_L1, b1, pt, cg, l);
  run_layer<16>(ahi, alo, pack, UB_L2, b2, pt, cg, l);
  run_layer<16>(ahi, alo, pack, UB_L3, b3, pt, cg, l);

  // ---------------- final layer: 256 -> 1 (vectorized dot) ----------------
  {
    int pl = tid >> 3, q = tid & 7;   // 8 threads/point, 32 elems each
    const unsigned short* hrow = ahi + pl * LDA + (q << 5);
    const unsigned short* lrow = alo + pl * LDA + (q << 5);
    const float* w4p = W4 + (q << 5);
    float sum = 0.0f;
#pragma unroll
    for (int c = 0; c < 4; ++c) {
      u32x4 th = *(const u32x4*)(hrow + (c << 3));
      u32x4 tl = *(const u32x4*)(lrow + (c << 3));
      float4 wA = *(const float4*)(w4p + (c << 3));
      float4 wB = *(const float4*)(w4p + (c << 3) + 4);
#pragma unroll
      for (int u = 0; u < 4; ++u) {
        unsigned hu = th[u], lu = tl[u];
        float v0 = __uint_as_float(hu << 16) + __uint_as_float(lu << 16);
        float v1 = __uint_as_float(hu & 0xffff0000u) + __uint_as_float(lu & 0xffff0000u);
        const float* wp = (u < 2) ? &wA.x : &wB.x;
        int base = (u & 1) << 1;
        sum = fmaf(v0, wp[base], sum);
        sum = fmaf(v1, wp[base + 1], sum);
      }
    }
    sum += __shfl_xor(sum, 1);
    sum += __shfl_xor(sum, 2);
    sum += __shfl_xor(sum, 4);
    if (q == 0) out[(size_t)blockIdx.x * MTILE + pl] = sum + b4[0];
  }
}

// ------------------------------- launcher ----------------------------------
extern "C" void kernel_launch(void* const* d_in, const int* in_sizes, int n_in,
                              void* d_out, int out_size, void* d_ws, size_t ws_size,
                              hipStream_t stream) {
  const float* x      = (const float*)d_in[0];
  const float* tables = (const float*)d_in[1];
  const float* W0 = (const float*)d_in[2];  const float* b0 = (const float*)d_in[3];
  const float* W1 = (const float*)d_in[4];  const float* b1 = (const float*)d_in[5];
  const float* W2 = (const float*)d_in[6];  const float* b2 = (const float*)d_in[7];
  const float* W3 = (const float*)d_in[8];  const float* b3 = (const float*)d_in[9];
  const float* W4 = (const float*)d_in[10]; const float* b4 = (const float*)d_in[11];
  unsigned short* pack = (unsigned short*)d_ws;
  float* out = (float*)d_out;

  LevelParams P;
  double bgrow = exp((log(512.0) - log(8.0)) / 15.0);
  for (int lvl = 0; lvl < 16; ++lvl) {
    double r = floor(8.0 * pow(bgrow, (double)lvl));
    P.res[lvl] = (float)r;
    double hsd = r * r;
    if (hsd > 4096.0) hsd = 4096.0;
    P.hsize[lvl] = (unsigned)hsd;
  }
  for (int lvl = 0; lvl < 8; ++lvl) {
    unsigned d = P.hsize[lvl];
    P.c16[lvl] = 65536u % d;
    unsigned long long nmax = 65535ULL * d;
    int s = 0;
    while (nmax * d >= (1ULL << (32 + s))) s++;
    P.sh[lvl] = s;
    P.M[lvl] = (unsigned)((1ULL << (32 + s)) / d + 1);
  }

  prep_pack<<<UNITS_TOTAL, 64, 0, stream>>>(W0, W1, W2, W3, pack);

  size_t smem_bytes = (size_t)ACT_ELEMS * 2 * 2;  // 67584
  hipFuncSetAttribute(reinterpret_cast<const void*>(inr_main),
                      hipFuncAttributeMaxDynamicSharedMemorySize, (int)smem_bytes);

  int nblocks = out_size / MTILE;  // 4096
  inr_main<<<nblocks, 512, smem_bytes, stream>>>(x, tables, b0, b1, b2, b3, W4, b4,
                                                 pack, out, P);
}

// Round 8
// 315.319 us; speedup vs baseline: 1.0707x; 1.0707x over previous
//
#include <hip/hip_runtime.h>
#include <math.h>

// ---------------------------------------------------------------------------
// HashGrid INR fused kernel for MI355X (gfx950) — round 8
//   r6 structure (cq waves: 32 cols x 64 pts, no weight redundancy) +
//   independent-accumulator split (accA: 1-dep, accB: 2-dep chains) to cover
//   dependent-MFMA latency. bf16x3 on 32x32x16.
// ---------------------------------------------------------------------------

typedef __bf16 bf16x8 __attribute__((ext_vector_type(8)));
typedef float  f32x16 __attribute__((ext_vector_type(16)));
typedef unsigned int u32x4 __attribute__((ext_vector_type(4)));
typedef unsigned int u32x2 __attribute__((ext_vector_type(2)));

struct LevelParams {
  float res[16];
  unsigned hsize[16];
  unsigned M[8];     // magic multiplier for levels 0..7
  unsigned c16[8];   // 65536 % d
  int      sh[8];    // post-mulhi shift
};

static constexpr int MTILE = 64;          // points per block
static constexpr int LDA   = 264;         // act row stride (elems); 528B = 33x16B slots
static constexpr int ACT_ELEMS = MTILE * LDA;
// pack unit = (s, cq): 32 cols x 16 k, [hi 512 | lo 512] bf16 = 2KB
static constexpr int UB_L0 = 0, UB_L1 = 24, UB_L2 = 152, UB_L3 = 280;
static constexpr int UNITS_TOTAL = 408;

__device__ __forceinline__ unsigned short f32_to_bf16_rne(float f) {
  unsigned u = __float_as_uint(f);
  unsigned r = (u + 0x7fffu + ((u >> 16) & 1u)) >> 16;
  return (unsigned short)r;
}
__device__ __forceinline__ float bf16_bits_to_f32(unsigned u16bits) {
  return __uint_as_float(u16bits << 16);
}
__device__ __forceinline__ unsigned pack_hi(unsigned u0, unsigned u1) {
  return (u0 >> 16) | (u1 & 0xffff0000u);   // trunc bf16 of (v0,v1) packed
}

// --------------------------- weight packing --------------------------------
// mapping: out-col = cq*32 + (l&31), k = s*16 + 8*(l>>5) + e
__global__ void prep_pack(const float* __restrict__ W0, const float* __restrict__ W1,
                          const float* __restrict__ W2, const float* __restrict__ W3,
                          unsigned short* __restrict__ pack) {
  int b = blockIdx.x;
  int l = threadIdx.x;
  const float* W; int K, s, cq;
  if (b < UB_L1) { W = W0; K = 33; s = b >> 3; cq = b & 7; }
  else {
    int b2 = b - UB_L1; int ly = b2 >> 7; int r = b2 & 127;
    W = (ly == 0) ? W1 : (ly == 1) ? W2 : W3; K = 256; s = r >> 3; cq = r & 7;
  }
  int col = (cq << 5) + (l & 31);
  int kb  = (s << 4) + ((l >> 5) << 3);
  unsigned short* dst = pack + (size_t)b * 1024 + l * 8;
#pragma unroll
  for (int e = 0; e < 8; ++e) {
    int k = kb + e;
    float v = (k < K) ? W[k * 256 + col] : 0.0f;
    unsigned u = __float_as_uint(v);
    unsigned short h = (unsigned short)(u >> 16);           // truncation hi
    float hf = bf16_bits_to_f32(u >> 16);
    unsigned short lo = f32_to_bf16_rne(v - hf);
    dst[e]       = h;
    dst[512 + e] = lo;
  }
}

// ------------------------------ layer body ---------------------------------
// 8 waves, wave cq owns cols [cq*32, cq*32+32) x all 64 points.
// A = weights (lane&31 -> out channel), B = acts (lane&31 -> point).
// D (32x32): col = lane&31 = point; row = (r&3)+8*(r>>2)+4*(lane>>5) = channel.
// Accumulator split per point-half: accA (Wh*AH only, independent each step),
// accB (Wl*AH -> Wh*AL, 2-chain). Final D = accA + accB.
template<int S>
__device__ __forceinline__ void run_layer(unsigned short* __restrict__ ahi,
                                          unsigned short* __restrict__ alo,
                                          const unsigned short* __restrict__ pack,
                                          int ubase,
                                          const float* __restrict__ bias,
                                          int cq, int l) {
  f32x16 accA0 = (f32x16)0.0f, accB0 = (f32x16)0.0f;
  f32x16 accA1 = (f32x16)0.0f, accB1 = (f32x16)0.0f;
  const int i31 = l & 31, p = l >> 5;

  const unsigned short* a0h = ahi + i31 * LDA + (p << 3);
  const unsigned short* a1h = ahi + (32 + i31) * LDA + (p << 3);
  const unsigned short* a0l = alo + i31 * LDA + (p << 3);
  const unsigned short* a1l = alo + (32 + i31) * LDA + (p << 3);
  const unsigned short* wb  = pack + (size_t)(ubase + cq) * 1024 + l * 8;

  // prefetched weight pipeline (step stride = 8 units = 8192 shorts)
  u32x4 wh = *(const u32x4*)(wb);
  u32x4 wl = *(const u32x4*)(wb + 512);
#pragma unroll
  for (int s = 0; s < S; ++s) {
    u32x4 whn = wh, wln = wl;
    if (s + 1 < S) {
      whn = *(const u32x4*)(wb + (size_t)(s + 1) * 8192);
      wln = *(const u32x4*)(wb + (size_t)(s + 1) * 8192 + 512);
    }
    bf16x8 ah0 = __builtin_bit_cast(bf16x8, *(const u32x4*)(a0h + (s << 4)));
    bf16x8 al0 = __builtin_bit_cast(bf16x8, *(const u32x4*)(a0l + (s << 4)));
    bf16x8 ah1 = __builtin_bit_cast(bf16x8, *(const u32x4*)(a1h + (s << 4)));
    bf16x8 al1 = __builtin_bit_cast(bf16x8, *(const u32x4*)(a1l + (s << 4)));
    bf16x8 W_h = __builtin_bit_cast(bf16x8, wh);
    bf16x8 W_l = __builtin_bit_cast(bf16x8, wl);
    // 6 MFMAs: accA* independent; accB* pairs at issue-distance 2
    accA0 = __builtin_amdgcn_mfma_f32_32x32x16_bf16(W_h, ah0, accA0, 0, 0, 0);
    accA1 = __builtin_amdgcn_mfma_f32_32x32x16_bf16(W_h, ah1, accA1, 0, 0, 0);
    accB0 = __builtin_amdgcn_mfma_f32_32x32x16_bf16(W_l, ah0, accB0, 0, 0, 0);
    accB1 = __builtin_amdgcn_mfma_f32_32x32x16_bf16(W_l, ah1, accB1, 0, 0, 0);
    accB0 = __builtin_amdgcn_mfma_f32_32x32x16_bf16(W_h, al0, accB0, 0, 0, 0);
    accB1 = __builtin_amdgcn_mfma_f32_32x32x16_bf16(W_h, al1, accB1, 0, 0, 0);
    wh = whn; wl = wln;
  }
  __syncthreads();   // all reads of act done -> safe to overwrite

#pragma unroll
  for (int pt = 0; pt < 2; ++pt) {
    int arow = (pt << 5) + i31;
    f32x16 A = pt ? accA1 : accA0;        // pt is unroll-constant
    f32x16 B = pt ? accB1 : accB0;
#pragma unroll
    for (int g = 0; g < 4; ++g) {
      int chb = (cq << 5) + (g << 3) + (p << 2);
      float4 bv = *(const float4*)(bias + chb);
      float v0 = fmaxf((A[4 * g + 0] + B[4 * g + 0]) + bv.x, 0.0f);
      float v1 = fmaxf((A[4 * g + 1] + B[4 * g + 1]) + bv.y, 0.0f);
      float v2 = fmaxf((A[4 * g + 2] + B[4 * g + 2]) + bv.z, 0.0f);
      float v3 = fmaxf((A[4 * g + 3] + B[4 * g + 3]) + bv.w, 0.0f);
      unsigned u0 = __float_as_uint(v0), u1 = __float_as_uint(v1);
      unsigned u2 = __float_as_uint(v2), u3 = __float_as_uint(v3);
      u32x2 hw = { pack_hi(u0, u1), pack_hi(u2, u3) };
      float l0 = v0 - __uint_as_float(u0 & 0xffff0000u);
      float l1 = v1 - __uint_as_float(u1 & 0xffff0000u);
      float l2 = v2 - __uint_as_float(u2 & 0xffff0000u);
      float l3 = v3 - __uint_as_float(u3 & 0xffff0000u);
      u32x2 lw = { pack_hi(__float_as_uint(l0), __float_as_uint(l1)),
                   pack_hi(__float_as_uint(l2), __float_as_uint(l3)) };
      int base = arow * LDA + chb;
      *(u32x2*)(ahi + base) = hw;
      *(u32x2*)(alo + base) = lw;
    }
  }
  __syncthreads();
}

// ------------------------------ main kernel --------------------------------
__global__ __launch_bounds__(512, 4) void inr_main(
    const float* __restrict__ x, const float* __restrict__ tables,
    const float* __restrict__ b0, const float* __restrict__ b1,
    const float* __restrict__ b2, const float* __restrict__ b3,
    const float* __restrict__ W4, const float* __restrict__ b4,
    const unsigned short* __restrict__ pack, float* __restrict__ out,
    LevelParams P) {
  extern __shared__ char smem[];
  unsigned short* ahi = (unsigned short*)smem;
  unsigned short* alo = ahi + ACT_ELEMS;

  const int tid = threadIdx.x;

  // -------- encode: 8 threads/point; thread q does level q (magic) + q+8 (AND)
  {
    int pl = tid >> 3, q = tid & 7;
    size_t pidx = (size_t)blockIdx.x * MTILE + pl;
    float x0 = x[3 * pidx + 0], x1 = x[3 * pidx + 1], x2 = x[3 * pidx + 2];
    float f_lo0, f_lo1, f_hi0, f_hi1;

    {   // level q: hashed, exact magic modulo
      float rf = P.res[q];
      unsigned d = P.hsize[q], c = P.c16[q], M = P.M[q];
      int sh = P.sh[q];
      float xs0 = x0 * rf, xs1 = x1 * rf;
      float fl0 = floorf(xs0), fl1 = floorf(xs1);
      float f0 = xs0 - fl0, f1 = xs1 - fl1;
      int i0 = (int)fl0, i1 = (int)fl1;
      unsigned ua0 = (unsigned)i0, ua1 = (unsigned)(i0 + 1);
      unsigned vb0 = (unsigned)i1 * 2654435761u;
      unsigned vb1 = (unsigned)(i1 + 1) * 2654435761u;
      const float* tl = tables + ((size_t)q << 13);
      float g0 = 1.0f - f0, g1 = 1.0f - f1;
      unsigned e0 = ua0 ^ vb0, e1 = ua0 ^ vb1, e2 = ua1 ^ vb0, e3 = ua1 ^ vb1;
      unsigned n0 = (e0 >> 16) * c + (e0 & 0xffffu);
      unsigned n1 = (e1 >> 16) * c + (e1 & 0xffffu);
      unsigned n2 = (e2 >> 16) * c + (e2 & 0xffffu);
      unsigned n3 = (e3 >> 16) * c + (e3 & 0xffffu);
      unsigned h0 = n0 - (__umulhi(n0, M) >> sh) * d;
      unsigned h1 = n1 - (__umulhi(n1, M) >> sh) * d;
      unsigned h2 = n2 - (__umulhi(n2, M) >> sh) * d;
      unsigned h3 = n3 - (__umulhi(n3, M) >> sh) * d;
      float a0 = 0.0f, a1 = 0.0f;
      { float w = g0 * g1; a0 += w * tl[2*h0]; a1 += w * tl[2*h0+1]; }
      { float w = g0 * f1; a0 += w * tl[2*h1]; a1 += w * tl[2*h1+1]; }
      { float w = f0 * g1; a0 += w * tl[2*h2]; a1 += w * tl[2*h2+1]; }
      { float w = f0 * f1; a0 += w * tl[2*h3]; a1 += w * tl[2*h3+1]; }
      f_lo0 = a0; f_lo1 = a1;
    }
    {   // level q+8: hsize == 4096 -> AND
      int lv = q + 8;
      float rf = P.res[lv];
      float xs0 = x0 * rf, xs1 = x1 * rf;
      float fl0 = floorf(xs0), fl1 = floorf(xs1);
      float f0 = xs0 - fl0, f1 = xs1 - fl1;
      int i0 = (int)fl0, i1 = (int)fl1;
      unsigned ua0 = (unsigned)i0, ua1 = (unsigned)(i0 + 1);
      unsigned vb0 = (unsigned)i1 * 2654435761u;
      unsigned vb1 = (unsigned)(i1 + 1) * 2654435761u;
      const float* tl = tables + ((size_t)lv << 13);
      float g0 = 1.0f - f0, g1 = 1.0f - f1;
      unsigned h0 = (ua0 ^ vb0) & 4095u, h1 = (ua0 ^ vb1) & 4095u;
      unsigned h2 = (ua1 ^ vb0) & 4095u, h3 = (ua1 ^ vb1) & 4095u;
      float a0 = 0.0f, a1 = 0.0f;
      { float w = g0 * g1; a0 += w * tl[2*h0]; a1 += w * tl[2*h0+1]; }
      { float w = g0 * f1; a0 += w * tl[2*h1]; a1 += w * tl[2*h1+1]; }
      { float w = f0 * g1; a0 += w * tl[2*h2]; a1 += w * tl[2*h2+1]; }
      { float w = f0 * f1; a0 += w * tl[2*h3]; a1 += w * tl[2*h3+1]; }
      f_hi0 = a0; f_hi1 = a1;
    }
    {   // store: level q -> cols {2q,2q+1}; level q+8 -> cols {16+2q,17+2q}
      int rowb = pl * LDA;
      unsigned u0 = __float_as_uint(f_lo0), u1 = __float_as_uint(f_lo1);
      unsigned u2 = __float_as_uint(f_hi0), u3 = __float_as_uint(f_hi1);
      float l0 = f_lo0 - __uint_as_float(u0 & 0xffff0000u);
      float l1 = f_lo1 - __uint_as_float(u1 & 0xffff0000u);
      float l2 = f_hi0 - __uint_as_float(u2 & 0xffff0000u);
      float l3 = f_hi1 - __uint_as_float(u3 & 0xffff0000u);
      *(unsigned*)(ahi + rowb + 2*q)      = pack_hi(u0, u1);
      *(unsigned*)(ahi + rowb + 16 + 2*q) = pack_hi(u2, u3);
      *(unsigned*)(alo + rowb + 2*q)      = pack_hi(__float_as_uint(l0), __float_as_uint(l1));
      *(unsigned*)(alo + rowb + 16 + 2*q) = pack_hi(__float_as_uint(l2), __float_as_uint(l3));
    }
    {   // tail cols 32..47: [x2, 0, 0, ...]; thread q covers {32+2q, 33+2q}
      int base = pl * LDA + 32 + 2*q;
      if (q == 0) {
        unsigned u0 = __float_as_uint(x2);
        float l0 = x2 - __uint_as_float(u0 & 0xffff0000u);
        *(unsigned*)(ahi + base) = u0 >> 16;
        *(unsigned*)(alo + base) = __float_as_uint(l0) >> 16;
      } else {
        *(unsigned*)(ahi + base) = 0u;
        *(unsigned*)(alo + base) = 0u;
      }
    }
  }
  __syncthreads();

  const int l  = tid & 63;
  const int cq = tid >> 6;      // 8 waves: each owns 32 output cols

  run_layer<3>(ahi, alo, pack, UB_L0, b0, cq, l);
  run_layer<16>(ahi, alo, pack, UB_L1, b1, cq, l);
  run_layer<16>(ahi, alo, pack, UB_L2, b2, cq, l);
  run_layer<16>(ahi, alo, pack, UB_L3, b3, cq, l);

  // ---------------- final layer: 256 -> 1 (vectorized dot) ----------------
  {
    int pl = tid >> 3, q = tid & 7;   // 8 threads/point, 32 elems each
    const unsigned short* hrow = ahi + pl * LDA + (q << 5);
    const unsigned short* lrow = alo + pl * LDA + (q << 5);
    const float* w4p = W4 + (q << 5);
    float sum = 0.0f;
#pragma unroll
    for (int c = 0; c < 4; ++c) {
      u32x4 th = *(const u32x4*)(hrow + (c << 3));
      u32x4 tl = *(const u32x4*)(lrow + (c << 3));
      float4 wA = *(const float4*)(w4p + (c << 3));
      float4 wB = *(const float4*)(w4p + (c << 3) + 4);
#pragma unroll
      for (int u = 0; u < 4; ++u) {
        unsigned hu = th[u], lu = tl[u];
        float v0 = __uint_as_float(hu << 16) + __uint_as_float(lu << 16);
        float v1 = __uint_as_float(hu & 0xffff0000u) + __uint_as_float(lu & 0xffff0000u);
        const float* wp = (u < 2) ? &wA.x : &wB.x;
        int base = (u & 1) << 1;
        sum = fmaf(v0, wp[base], sum);
        sum = fmaf(v1, wp[base + 1], sum);
      }
    }
    sum += __shfl_xor(sum, 1);
    sum += __shfl_xor(sum, 2);
    sum += __shfl_xor(sum, 4);
    if (q == 0) out[(size_t)blockIdx.x * MTILE + pl] = sum + b4[0];
  }
}

// ------------------------------- launcher ----------------------------------
extern "C" void kernel_launch(void* const* d_in, const int* in_sizes, int n_in,
                              void* d_out, int out_size, void* d_ws, size_t ws_size,
                              hipStream_t stream) {
  const float* x      = (const float*)d_in[0];
  const float* tables = (const float*)d_in[1];
  const float* W0 = (const float*)d_in[2];  const float* b0 = (const float*)d_in[3];
  const float* W1 = (const float*)d_in[4];  const float* b1 = (const float*)d_in[5];
  const float* W2 = (const float*)d_in[6];  const float* b2 = (const float*)d_in[7];
  const float* W3 = (const float*)d_in[8];  const float* b3 = (const float*)d_in[9];
  const float* W4 = (const float*)d_in[10]; const float* b4 = (const float*)d_in[11];
  unsigned short* pack = (unsigned short*)d_ws;
  float* out = (float*)d_out;

  LevelParams P;
  double bgrow = exp((log(512.0) - log(8.0)) / 15.0);
  for (int lvl = 0; lvl < 16; ++lvl) {
    double r = floor(8.0 * pow(bgrow, (double)lvl));
    P.res[lvl] = (float)r;
    double hsd = r * r;
    if (hsd > 4096.0) hsd = 4096.0;
    P.hsize[lvl] = (unsigned)hsd;
  }
  for (int lvl = 0; lvl < 8; ++lvl) {
    unsigned d = P.hsize[lvl];
    P.c16[lvl] = 65536u % d;
    unsigned long long nmax = 65535ULL * d;
    int s = 0;
    while (nmax * d >= (1ULL << (32 + s))) s++;
    P.sh[lvl] = s;
    P.M[lvl] = (unsigned)((1ULL << (32 + s)) / d + 1);
  }

  prep_pack<<<UNITS_TOTAL, 64, 0, stream>>>(W0, W1, W2, W3, pack);

  size_t smem_bytes = (size_t)ACT_ELEMS * 2 * 2;  // 67584
  hipFuncSetAttribute(reinterpret_cast<const void*>(inr_main),
                      hipFuncAttributeMaxDynamicSharedMemorySize, (int)smem_bytes);

  int nblocks = out_size / MTILE;  // 4096
  inr_main<<<nblocks, 512, smem_bytes, stream>>>(x, tables, b0, b1, b2, b3, W4, b4,
                                                 pack, out, P);
}

// Round 9
// 296.415 us; speedup vs baseline: 1.1390x; 1.0638x over previous
//
#include <hip/hip_runtime.h>
#include <math.h>

// ---------------------------------------------------------------------------
// HashGrid INR fused kernel for MI355X (gfx950) — round 9
//   4-wave blocks (256 thr), wave = 64 pts x 64 cols (halves LDS act traffic
//   vs r6; weight traffic unchanged), 3-slot 2-deep software pipeline,
//   bf16x3 on 32x32x16, magic-mod encode.
// ---------------------------------------------------------------------------

typedef __bf16 bf16x8 __attribute__((ext_vector_type(8)));
typedef float  f32x16 __attribute__((ext_vector_type(16)));
typedef unsigned int u32x4 __attribute__((ext_vector_type(4)));
typedef unsigned int u32x2 __attribute__((ext_vector_type(2)));

struct LevelParams {
  float res[16];
  unsigned hsize[16];
  unsigned M[8];     // magic multiplier for levels 0..7
  unsigned c16[8];   // 65536 % d
  int      sh[8];    // post-mulhi shift
};

static constexpr int MTILE = 64;          // points per block
static constexpr int LDA   = 264;         // act row stride (elems); 528B = 33x16B slots
static constexpr int ACT_ELEMS = MTILE * LDA;
// pack unit = (s, cq): 32 cols x 16 k, [hi 512 | lo 512] bf16 = 2KB
static constexpr int UB_L0 = 0, UB_L1 = 24, UB_L2 = 152, UB_L3 = 280;
static constexpr int UNITS_TOTAL = 408;

__device__ __forceinline__ unsigned short f32_to_bf16_rne(float f) {
  unsigned u = __float_as_uint(f);
  unsigned r = (u + 0x7fffu + ((u >> 16) & 1u)) >> 16;
  return (unsigned short)r;
}
__device__ __forceinline__ float bf16_bits_to_f32(unsigned u16bits) {
  return __uint_as_float(u16bits << 16);
}
__device__ __forceinline__ unsigned pack_hi(unsigned u0, unsigned u1) {
  return (u0 >> 16) | (u1 & 0xffff0000u);   // trunc bf16 of (v0,v1) packed
}

// --------------------------- weight packing --------------------------------
// mapping: out-col = cq*32 + (l&31), k = s*16 + 8*(l>>5) + e
__global__ void prep_pack(const float* __restrict__ W0, const float* __restrict__ W1,
                          const float* __restrict__ W2, const float* __restrict__ W3,
                          unsigned short* __restrict__ pack) {
  int b = blockIdx.x;
  int l = threadIdx.x;
  const float* W; int K, s, cq;
  if (b < UB_L1) { W = W0; K = 33; s = b >> 3; cq = b & 7; }
  else {
    int b2 = b - UB_L1; int ly = b2 >> 7; int r = b2 & 127;
    W = (ly == 0) ? W1 : (ly == 1) ? W2 : W3; K = 256; s = r >> 3; cq = r & 7;
  }
  int col = (cq << 5) + (l & 31);
  int kb  = (s << 4) + ((l >> 5) << 3);
  unsigned short* dst = pack + (size_t)b * 1024 + l * 8;
#pragma unroll
  for (int e = 0; e < 8; ++e) {
    int k = kb + e;
    float v = (k < K) ? W[k * 256 + col] : 0.0f;
    unsigned u = __float_as_uint(v);
    unsigned short h = (unsigned short)(u >> 16);           // truncation hi
    float hf = bf16_bits_to_f32(u >> 16);
    unsigned short lo = f32_to_bf16_rne(v - hf);
    dst[e]       = h;
    dst[512 + e] = lo;
  }
}

// ---------------------------- encode helpers -------------------------------
__device__ __forceinline__ void enc_magic(float x0, float x1, const LevelParams& P,
                                          int lvl, const float* __restrict__ tables,
                                          float& o0, float& o1) {
  float rf = P.res[lvl];
  unsigned d = P.hsize[lvl], c = P.c16[lvl], M = P.M[lvl];
  int sh = P.sh[lvl];
  float xs0 = x0 * rf, xs1 = x1 * rf;
  float fl0 = floorf(xs0), fl1 = floorf(xs1);
  float f0 = xs0 - fl0, f1 = xs1 - fl1;
  int i0 = (int)fl0, i1 = (int)fl1;
  unsigned ua0 = (unsigned)i0, ua1 = (unsigned)(i0 + 1);
  unsigned vb0 = (unsigned)i1 * 2654435761u;
  unsigned vb1 = (unsigned)(i1 + 1) * 2654435761u;
  const float* tl = tables + ((size_t)lvl << 13);
  float g0 = 1.0f - f0, g1 = 1.0f - f1;
  unsigned e0 = ua0 ^ vb0, e1 = ua0 ^ vb1, e2 = ua1 ^ vb0, e3 = ua1 ^ vb1;
  unsigned n0 = (e0 >> 16) * c + (e0 & 0xffffu);
  unsigned n1 = (e1 >> 16) * c + (e1 & 0xffffu);
  unsigned n2 = (e2 >> 16) * c + (e2 & 0xffffu);
  unsigned n3 = (e3 >> 16) * c + (e3 & 0xffffu);
  unsigned h0 = n0 - (__umulhi(n0, M) >> sh) * d;
  unsigned h1 = n1 - (__umulhi(n1, M) >> sh) * d;
  unsigned h2 = n2 - (__umulhi(n2, M) >> sh) * d;
  unsigned h3 = n3 - (__umulhi(n3, M) >> sh) * d;
  float a0 = 0.0f, a1 = 0.0f;
  { float w = g0 * g1; a0 += w * tl[2*h0]; a1 += w * tl[2*h0+1]; }
  { float w = g0 * f1; a0 += w * tl[2*h1]; a1 += w * tl[2*h1+1]; }
  { float w = f0 * g1; a0 += w * tl[2*h2]; a1 += w * tl[2*h2+1]; }
  { float w = f0 * f1; a0 += w * tl[2*h3]; a1 += w * tl[2*h3+1]; }
  o0 = a0; o1 = a1;
}
__device__ __forceinline__ void enc_and(float x0, float x1, const LevelParams& P,
                                        int lvl, const float* __restrict__ tables,
                                        float& o0, float& o1) {
  float rf = P.res[lvl];
  float xs0 = x0 * rf, xs1 = x1 * rf;
  float fl0 = floorf(xs0), fl1 = floorf(xs1);
  float f0 = xs0 - fl0, f1 = xs1 - fl1;
  int i0 = (int)fl0, i1 = (int)fl1;
  unsigned ua0 = (unsigned)i0, ua1 = (unsigned)(i0 + 1);
  unsigned vb0 = (unsigned)i1 * 2654435761u;
  unsigned vb1 = (unsigned)(i1 + 1) * 2654435761u;
  const float* tl = tables + ((size_t)lvl << 13);
  float g0 = 1.0f - f0, g1 = 1.0f - f1;
  unsigned h0 = (ua0 ^ vb0) & 4095u, h1 = (ua0 ^ vb1) & 4095u;
  unsigned h2 = (ua1 ^ vb0) & 4095u, h3 = (ua1 ^ vb1) & 4095u;
  float a0 = 0.0f, a1 = 0.0f;
  { float w = g0 * g1; a0 += w * tl[2*h0]; a1 += w * tl[2*h0+1]; }
  { float w = g0 * f1; a0 += w * tl[2*h1]; a1 += w * tl[2*h1+1]; }
  { float w = f0 * g1; a0 += w * tl[2*h2]; a1 += w * tl[2*h2+1]; }
  { float w = f0 * f1; a0 += w * tl[2*h3]; a1 += w * tl[2*h3+1]; }
  o0 = a0; o1 = a1;
}
__device__ __forceinline__ void store_pair(unsigned short* ahi, unsigned short* alo,
                                           int idx, float v0, float v1) {
  unsigned u0 = __float_as_uint(v0), u1 = __float_as_uint(v1);
  float l0 = v0 - __uint_as_float(u0 & 0xffff0000u);
  float l1 = v1 - __uint_as_float(u1 & 0xffff0000u);
  *(unsigned*)(ahi + idx) = pack_hi(u0, u1);
  *(unsigned*)(alo + idx) = pack_hi(__float_as_uint(l0), __float_as_uint(l1));
}

// ------------------------------ layer body ---------------------------------
// 4 waves, wave cg owns cols [cg*64, cg*64+64) x all 64 points.
// A = weights (lane&31 -> out channel), B = acts (lane&31 -> point).
// D (32x32): col = lane&31 = point; row = (r&3)+8*(r>>2)+4*(lane>>5) = channel.
// 3-slot rotating buffers, 2-deep prefetch (all indices compile-time).
template<int S>
__device__ __forceinline__ void run_layer(unsigned short* __restrict__ ahi,
                                          unsigned short* __restrict__ alo,
                                          const unsigned short* __restrict__ pack,
                                          int ubase,
                                          const float* __restrict__ bias,
                                          int cg, int l) {
  f32x16 acc00 = (f32x16)0.0f, acc01 = (f32x16)0.0f;
  f32x16 acc10 = (f32x16)0.0f, acc11 = (f32x16)0.0f;
  const int i31 = l & 31, p = l >> 5;

  const unsigned short* a0h = ahi + i31 * LDA + (p << 3);
  const unsigned short* a1h = ahi + (32 + i31) * LDA + (p << 3);
  const unsigned short* a0l = alo + i31 * LDA + (p << 3);
  const unsigned short* a1l = alo + (32 + i31) * LDA + (p << 3);
  const unsigned short* wb  = pack + (size_t)(ubase + (cg << 1)) * 1024 + l * 8;

  u32x4 A[3][4];   // [slot][a0h,a0l,a1h,a1l]
  u32x4 W[3][4];   // [slot][wh0,wl0,wh1,wl1]

#define LOADSTEP(j, st)                                                        \
  do {                                                                         \
    A[j][0] = *(const u32x4*)(a0h + ((st) << 4));                              \
    A[j][1] = *(const u32x4*)(a0l + ((st) << 4));                              \
    A[j][2] = *(const u32x4*)(a1h + ((st) << 4));                              \
    A[j][3] = *(const u32x4*)(a1l + ((st) << 4));                              \
    const unsigned short* wp = wb + (size_t)(st) * 8192;                       \
    W[j][0] = *(const u32x4*)(wp);                                             \
    W[j][1] = *(const u32x4*)(wp + 512);                                       \
    W[j][2] = *(const u32x4*)(wp + 1024);                                      \
    W[j][3] = *(const u32x4*)(wp + 1536);                                      \
  } while (0)

  LOADSTEP(0, 0);
  if (S > 1) LOADSTEP(1, 1);

#pragma unroll
  for (int s = 0; s < S; ++s) {
    if (s + 2 < S) { const int j = (s + 2) % 3; LOADSTEP(j, s + 2); }
    const int sl = s % 3;
    bf16x8 AH0 = __builtin_bit_cast(bf16x8, A[sl][0]);
    bf16x8 AL0 = __builtin_bit_cast(bf16x8, A[sl][1]);
    bf16x8 AH1 = __builtin_bit_cast(bf16x8, A[sl][2]);
    bf16x8 AL1 = __builtin_bit_cast(bf16x8, A[sl][3]);
    bf16x8 Wh0 = __builtin_bit_cast(bf16x8, W[sl][0]);
    bf16x8 Wl0 = __builtin_bit_cast(bf16x8, W[sl][1]);
    bf16x8 Wh1 = __builtin_bit_cast(bf16x8, W[sl][2]);
    bf16x8 Wl1 = __builtin_bit_cast(bf16x8, W[sl][3]);
    acc00 = __builtin_amdgcn_mfma_f32_32x32x16_bf16(Wh0, AH0, acc00, 0, 0, 0);
    acc01 = __builtin_amdgcn_mfma_f32_32x32x16_bf16(Wh1, AH0, acc01, 0, 0, 0);
    acc10 = __builtin_amdgcn_mfma_f32_32x32x16_bf16(Wh0, AH1, acc10, 0, 0, 0);
    acc11 = __builtin_amdgcn_mfma_f32_32x32x16_bf16(Wh1, AH1, acc11, 0, 0, 0);
    acc00 = __builtin_amdgcn_mfma_f32_32x32x16_bf16(Wl0, AH0, acc00, 0, 0, 0);
    acc01 = __builtin_amdgcn_mfma_f32_32x32x16_bf16(Wl1, AH0, acc01, 0, 0, 0);
    acc10 = __builtin_amdgcn_mfma_f32_32x32x16_bf16(Wl0, AH1, acc10, 0, 0, 0);
    acc11 = __builtin_amdgcn_mfma_f32_32x32x16_bf16(Wl1, AH1, acc11, 0, 0, 0);
    acc00 = __builtin_amdgcn_mfma_f32_32x32x16_bf16(Wh0, AL0, acc00, 0, 0, 0);
    acc01 = __builtin_amdgcn_mfma_f32_32x32x16_bf16(Wh1, AL0, acc01, 0, 0, 0);
    acc10 = __builtin_amdgcn_mfma_f32_32x32x16_bf16(Wh0, AL1, acc10, 0, 0, 0);
    acc11 = __builtin_amdgcn_mfma_f32_32x32x16_bf16(Wh1, AL1, acc11, 0, 0, 0);
  }
#undef LOADSTEP
  __syncthreads();   // all reads of act done -> safe to overwrite

#pragma unroll
  for (int pt = 0; pt < 2; ++pt) {
#pragma unroll
    for (int c = 0; c < 2; ++c) {
      f32x16 Acc = pt ? (c ? acc11 : acc10) : (c ? acc01 : acc00);
      int arow = (pt << 5) + i31;
      int colb = (cg << 6) + (c << 5) + (p << 2);
#pragma unroll
      for (int g = 0; g < 4; ++g) {
        int chb = colb + (g << 3);
        float4 bv = *(const float4*)(bias + chb);
        float v0 = fmaxf(Acc[4 * g + 0] + bv.x, 0.0f);
        float v1 = fmaxf(Acc[4 * g + 1] + bv.y, 0.0f);
        float v2 = fmaxf(Acc[4 * g + 2] + bv.z, 0.0f);
        float v3 = fmaxf(Acc[4 * g + 3] + bv.w, 0.0f);
        unsigned u0 = __float_as_uint(v0), u1 = __float_as_uint(v1);
        unsigned u2 = __float_as_uint(v2), u3 = __float_as_uint(v3);
        u32x2 hw = { pack_hi(u0, u1), pack_hi(u2, u3) };
        float l0 = v0 - __uint_as_float(u0 & 0xffff0000u);
        float l1 = v1 - __uint_as_float(u1 & 0xffff0000u);
        float l2 = v2 - __uint_as_float(u2 & 0xffff0000u);
        float l3 = v3 - __uint_as_float(u3 & 0xffff0000u);
        u32x2 lw = { pack_hi(__float_as_uint(l0), __float_as_uint(l1)),
                     pack_hi(__float_as_uint(l2), __float_as_uint(l3)) };
        int base = arow * LDA + chb;
        *(u32x2*)(ahi + base) = hw;
        *(u32x2*)(alo + base) = lw;
      }
    }
  }
  __syncthreads();
}

// ------------------------------ main kernel --------------------------------
__global__ __launch_bounds__(256, 2) void inr_main(
    const float* __restrict__ x, const float* __restrict__ tables,
    const float* __restrict__ b0, const float* __restrict__ b1,
    const float* __restrict__ b2, const float* __restrict__ b3,
    const float* __restrict__ W4, const float* __restrict__ b4,
    const unsigned short* __restrict__ pack, float* __restrict__ out,
    LevelParams P) {
  extern __shared__ char smem[];
  unsigned short* ahi = (unsigned short*)smem;
  unsigned short* alo = ahi + ACT_ELEMS;

  const int tid = threadIdx.x;

  // -------- encode: 4 threads/point; thread q does levels q, q+4 (magic),
  //          q+8, q+12 (AND); stores cols {2l, 2l+1} per level l.
  {
    int pl = tid >> 2, q = tid & 3;
    size_t pidx = (size_t)blockIdx.x * MTILE + pl;
    float x0 = x[3 * pidx + 0], x1 = x[3 * pidx + 1], x2 = x[3 * pidx + 2];
    int rowb = pl * LDA;
    float o0, o1;
    enc_magic(x0, x1, P, q,      tables, o0, o1); store_pair(ahi, alo, rowb + 2*q,      o0, o1);
    enc_magic(x0, x1, P, q + 4,  tables, o0, o1); store_pair(ahi, alo, rowb + 8 + 2*q,  o0, o1);
    enc_and  (x0, x1, P, q + 8,  tables, o0, o1); store_pair(ahi, alo, rowb + 16 + 2*q, o0, o1);
    enc_and  (x0, x1, P, q + 12, tables, o0, o1); store_pair(ahi, alo, rowb + 24 + 2*q, o0, o1);
    // tail cols 32..47: [x2, 0, ...]; thread q covers {32+4q .. 35+4q}
    int base = rowb + 32 + (q << 2);
    if (q == 0) {
      unsigned u0 = __float_as_uint(x2);
      float l0 = x2 - __uint_as_float(u0 & 0xffff0000u);
      u32x2 hw = { u0 >> 16, 0u };
      u32x2 lw = { __float_as_uint(l0) >> 16, 0u };
      *(u32x2*)(ahi + base) = hw;
      *(u32x2*)(alo + base) = lw;
    } else {
      u32x2 z = { 0u, 0u };
      *(u32x2*)(ahi + base) = z;
      *(u32x2*)(alo + base) = z;
    }
  }
  __syncthreads();

  const int l  = tid & 63;
  const int cg = tid >> 6;      // 4 waves: each owns 64 output cols

  run_layer<3>(ahi, alo, pack, UB_L0, b0, cg, l);
  run_layer<16>(ahi, alo, pack, UB_L1, b1, cg, l);
  run_layer<16>(ahi, alo, pack, UB_L2, b2, cg, l);
  run_layer<16>(ahi, alo, pack, UB_L3, b3, cg, l);

  // ---------------- final layer: 256 -> 1 (vectorized dot) ----------------
  {
    int pl = tid >> 2, q = tid & 3;   // 4 threads/point, 64 elems each
    const unsigned short* hrow = ahi + pl * LDA + (q << 6);
    const unsigned short* lrow = alo + pl * LDA + (q << 6);
    const float* w4p = W4 + (q << 6);
    float sum = 0.0f;
#pragma unroll
    for (int c = 0; c < 8; ++c) {
      u32x4 th = *(const u32x4*)(hrow + (c << 3));
      u32x4 tl = *(const u32x4*)(lrow + (c << 3));
      float4 wA = *(const float4*)(w4p + (c << 3));
      float4 wB = *(const float4*)(w4p + (c << 3) + 4);
#pragma unroll
      for (int u = 0; u < 4; ++u) {
        unsigned hu = th[u], lu = tl[u];
        float v0 = __uint_as_float(hu << 16) + __uint_as_float(lu << 16);
        float v1 = __uint_as_float(hu & 0xffff0000u) + __uint_as_float(lu & 0xffff0000u);
        const float* wp = (u < 2) ? &wA.x : &wB.x;
        int base = (u & 1) << 1;
        sum = fmaf(v0, wp[base], sum);
        sum = fmaf(v1, wp[base + 1], sum);
      }
    }
    sum += __shfl_xor(sum, 1);
    sum += __shfl_xor(sum, 2);
    if (q == 0) out[(size_t)blockIdx.x * MTILE + pl] = sum + b4[0];
  }
}

// ------------------------------- launcher ----------------------------------
extern "C" void kernel_launch(void* const* d_in, const int* in_sizes, int n_in,
                              void* d_out, int out_size, void* d_ws, size_t ws_size,
                              hipStream_t stream) {
  const float* x      = (const float*)d_in[0];
  const float* tables = (const float*)d_in[1];
  const float* W0 = (const float*)d_in[2];  const float* b0 = (const float*)d_in[3];
  const float* W1 = (const float*)d_in[4];  const float* b1 = (const float*)d_in[5];
  const float* W2 = (const float*)d_in[6];  const float* b2 = (const float*)d_in[7];
  const float* W3 = (const float*)d_in[8];  const float* b3 = (const float*)d_in[9];
  const float* W4 = (const float*)d_in[10]; const float* b4 = (const float*)d_in[11];
  unsigned short* pack = (unsigned short*)d_ws;
  float* out = (float*)d_out;

  LevelParams P;
  double bgrow = exp((log(512.0) - log(8.0)) / 15.0);
  for (int lvl = 0; lvl < 16; ++lvl) {
    double r = floor(8.0 * pow(bgrow, (double)lvl));
    P.res[lvl] = (float)r;
    double hsd = r * r;
    if (hsd > 4096.0) hsd = 4096.0;
    P.hsize[lvl] = (unsigned)hsd;
  }
  for (int lvl = 0; lvl < 8; ++lvl) {
    unsigned d = P.hsize[lvl];
    P.c16[lvl] = 65536u % d;
    unsigned long long nmax = 65535ULL * d;
    int s = 0;
    while (nmax * d >= (1ULL << (32 + s))) s++;
    P.sh[lvl] = s;
    P.M[lvl] = (unsigned)((1ULL << (32 + s)) / d + 1);
  }

  prep_pack<<<UNITS_TOTAL, 64, 0, stream>>>(W0, W1, W2, W3, pack);

  size_t smem_bytes = (size_t)ACT_ELEMS * 2 * 2;  // 67584
  hipFuncSetAttribute(reinterpret_cast<const void*>(inr_main),
                      hipFuncAttributeMaxDynamicSharedMemorySize, (int)smem_bytes);

  int nblocks = out_size / MTILE;  // 4096
  inr_main<<<nblocks, 256, smem_bytes, stream>>>(x, tables, b0, b1, b2, b3, W4, b4,
                                                 pack, out, P);
}